// Round 10
// baseline (1551.997 us; speedup 1.0000x reference)
//
#include <hip/hip_runtime.h>

#define N_NODES 100000
#define N_EDGES 600000
#define N_GRAPHS 1024
#define F_IN 32
#define GHC 128
#define NHID 512
#define NOUT 256
#define N_LAYERS 5
#define BN_EPS 1e-5f

typedef __attribute__((ext_vector_type(4))) float f32x4;
typedef __attribute__((ext_vector_type(8))) short bf16x8;

__device__ __forceinline__ unsigned short f2bf(float f) {
    unsigned int u = __float_as_uint(f);
    u = u + 0x7fffu + ((u >> 16) & 1u);
    return (unsigned short)(u >> 16);
}
__device__ __forceinline__ float bf2f(unsigned short h) {
    return __uint_as_float(((unsigned int)h) << 16);
}

// ==================== CSR build ====================
__global__ void deg_kernel(const int* __restrict__ dst, int* __restrict__ deg) {
    int e = blockIdx.x * blockDim.x + threadIdx.x;
    if (e < N_EDGES) atomicAdd(&deg[dst[e]], 1);
}

#define SCHUNK 1024
#define NCHUNKS ((N_NODES + SCHUNK - 1) / SCHUNK)   // 98

__global__ __launch_bounds__(1024)
void scan1_kernel(const int* __restrict__ deg, int* __restrict__ ptr, int* __restrict__ btot) {
    __shared__ int buf[SCHUNK];
    int t = threadIdx.x;
    int i = blockIdx.x * SCHUNK + t;
    int v = (i < N_NODES) ? deg[i] : 0;
    buf[t] = v;
    __syncthreads();
    for (int off = 1; off < SCHUNK; off <<= 1) {
        int u = (t >= off) ? buf[t - off] : 0;
        __syncthreads();
        buf[t] += u;
        __syncthreads();
    }
    if (i < N_NODES) ptr[i + 1] = buf[t];
    if (t == SCHUNK - 1) btot[blockIdx.x] = buf[t];
}

__global__ __launch_bounds__(128)
void scan2_kernel(int* __restrict__ btot) {
    __shared__ int buf[128];
    int t = threadIdx.x;
    int v = (t < NCHUNKS) ? btot[t] : 0;
    buf[t] = v;
    __syncthreads();
    for (int off = 1; off < 128; off <<= 1) {
        int u = (t >= off) ? buf[t - off] : 0;
        __syncthreads();
        buf[t] += u;
        __syncthreads();
    }
    if (t < NCHUNKS) btot[t] = buf[t] - v;
}

__global__ void scan3_kernel(int* __restrict__ ptr, const int* __restrict__ btot) {
    int i = blockIdx.x * blockDim.x + threadIdx.x;
    if (i < N_NODES) ptr[i + 1] += btot[i >> 10];
    if (i == 0) ptr[0] = 0;
}

__global__ void fill_kernel(const int* __restrict__ src, const int* __restrict__ dst,
                            int* __restrict__ cur, int* __restrict__ adj) {
    int e = blockIdx.x * blockDim.x + threadIdx.x;
    if (e >= N_EDGES) return;
    int p = atomicAdd(&cur[dst[e]], 1);
    adj[p] = src[e];
}

__global__ void gptr_kernel(const int* __restrict__ batch, int* __restrict__ gptr) {
    int g = blockIdx.x * blockDim.x + threadIdx.x;
    if (g > N_GRAPHS) return;
    int lo = 0, hi = N_NODES;
    while (lo < hi) { int mid = (lo + hi) >> 1; if (batch[mid] < g) lo = mid + 1; else hi = mid; }
    gptr[g] = lo;
}

// ==================== weight transpose + bf16 split: W[K][N] -> Wt_hi/lo [N][K] ====================
__global__ void wconv_kernel(const float* __restrict__ W, unsigned short* __restrict__ thi,
                             unsigned short* __restrict__ tlo, int K, int N) {
    int i = blockIdx.x * blockDim.x + threadIdx.x;
    if (i >= K * N) return;
    int k = i / N, n = i - k * N;
    float v = W[i];
    unsigned short h = f2bf(v);
    thi[(size_t)n * K + k] = h;
    tlo[(size_t)n * K + k] = f2bf(v - bf2f(h));
}

// ==================== gather aggregation (+ inline BN of previous layer) -> bf16 planes ====================
template<int F, bool BN>
__global__ __launch_bounds__(256)
void gather_agg_kernel(const float* __restrict__ x, const int* __restrict__ ptr,
                       const int* __restrict__ adj, const float* __restrict__ ss,
                       unsigned short* __restrict__ ahi, unsigned short* __restrict__ alo) {
    constexpr int F4 = F / 4;
    constexpr int NPB = 256 / F4;
    int f4 = threadIdx.x % F4;
    int n = blockIdx.x * NPB + threadIdx.x / F4;
    if (n >= N_NODES) return;
    const int fo = f4 * 4;
    float4 sc, sh;
    if (BN) { sc = *(const float4*)(ss + fo); sh = *(const float4*)(ss + GHC + fo); }
    float4 acc = *(const float4*)(x + (size_t)n * F + fo);
    if (BN) {
        acc.x = fmaxf(acc.x * sc.x + sh.x, 0.f); acc.y = fmaxf(acc.y * sc.y + sh.y, 0.f);
        acc.z = fmaxf(acc.z * sc.z + sh.z, 0.f); acc.w = fmaxf(acc.w * sc.w + sh.w, 0.f);
    }
    int p1 = ptr[n + 1];
    for (int p = ptr[n]; p < p1; ++p) {
        int s = adj[p];
        float4 v = *(const float4*)(x + (size_t)s * F + fo);
        if (BN) {
            v.x = fmaxf(v.x * sc.x + sh.x, 0.f); v.y = fmaxf(v.y * sc.y + sh.y, 0.f);
            v.z = fmaxf(v.z * sc.z + sh.z, 0.f); v.w = fmaxf(v.w * sc.w + sh.w, 0.f);
        }
        acc.x += v.x; acc.y += v.y; acc.z += v.z; acc.w += v.w;
    }
    ushort4 h4, l4;
    h4.x = f2bf(acc.x); l4.x = f2bf(acc.x - bf2f(h4.x));
    h4.y = f2bf(acc.y); l4.y = f2bf(acc.y - bf2f(h4.y));
    h4.z = f2bf(acc.z); l4.z = f2bf(acc.z - bf2f(h4.z));
    h4.w = f2bf(acc.w); l4.w = f2bf(acc.w - bf2f(h4.w));
    *(ushort4*)(ahi + (size_t)n * F + fo) = h4;
    *(ushort4*)(alo + (size_t)n * F + fo) = l4;
}

// ==================== fused MLP v3: h2 = (relu(A@W1+b1))@W2 + b2, + BN stats ====================
// 512 threads = 8 waves, tiled 4x2 (wave = 32 rows x 64 cols) for BOTH phases.
// hidden processed in TWO 128-col halves held in 64 KB LDS; acc2 persists in registers.
// K is a template param (32 or 128) so the phase-1 loop fully unrolls and loads pipeline.
// 3-term split: X*Y ~= Xh*Yh + Xh*Yl + Xl*Yh (fp32-level accuracy).
template<int K>
__global__ __launch_bounds__(512, 4)
void fused_mlp_kernel(const unsigned short* __restrict__ Ahi, const unsigned short* __restrict__ Alo,
                      const unsigned short* __restrict__ W1hi, const unsigned short* __restrict__ W1lo,
                      const unsigned short* __restrict__ W2hi, const unsigned short* __restrict__ W2lo,
                      const float* __restrict__ b1, const float* __restrict__ b2,
                      float* __restrict__ Of, float* __restrict__ bnsums,
                      int M)
{
    __shared__ __align__(16) unsigned short hidL[2][16][128][8];  // 64 KB hidden half planes
    __shared__ float sred[GHC], qred[GHC];

    const int tid = threadIdx.x;
    const int wv = tid >> 6, lane = tid & 63;
    const int r = lane & 15, g = lane >> 4;
    const int wm = wv >> 1, wn = wv & 1;     // 4x2 wave grid: 32-row band, 64-col band
    const int row0 = blockIdx.x * 128;

    if (tid < GHC) { sred[tid] = 0.f; qred[tid] = 0.f; }

    int arows[2];
#pragma unroll
    for (int i = 0; i < 2; ++i) {
        int rr = row0 + wm * 32 + i * 16 + r;
        arows[i] = rr < M ? rr : M - 1;
    }

    f32x4 acc2[2][4];
#pragma unroll
    for (int mi = 0; mi < 2; ++mi)
#pragma unroll
        for (int ni = 0; ni < 4; ++ni) acc2[mi][ni] = 0.f;

#pragma unroll
    for (int hh = 0; hh < 2; ++hh) {
        // ---------- phase 1: hidden half = A @ W1[:, hh*128 + 0..127] ----------
        f32x4 acc1[2][4];
#pragma unroll
        for (int mi = 0; mi < 2; ++mi)
#pragma unroll
            for (int ni = 0; ni < 4; ++ni) acc1[mi][ni] = 0.f;

#pragma unroll
        for (int k0 = 0; k0 < K; k0 += 32) {
            bf16x8 ah[2], al[2], bh[4], bl[4];
#pragma unroll
            for (int i = 0; i < 2; ++i) {
                const size_t ao = (size_t)arows[i] * K + k0 + g * 8;
                ah[i] = *(const bf16x8*)(Ahi + ao);
                al[i] = *(const bf16x8*)(Alo + ao);
            }
#pragma unroll
            for (int i = 0; i < 4; ++i) {
                const int n1g = hh * 128 + wn * 64 + i * 16 + r;
                const size_t wo = (size_t)n1g * K + k0 + g * 8;
                bh[i] = *(const bf16x8*)(W1hi + wo);
                bl[i] = *(const bf16x8*)(W1lo + wo);
            }
#pragma unroll
            for (int mi = 0; mi < 2; ++mi)
#pragma unroll
                for (int ni = 0; ni < 4; ++ni) {
                    acc1[mi][ni] = __builtin_amdgcn_mfma_f32_16x16x32_bf16(ah[mi], bh[ni], acc1[mi][ni], 0, 0, 0);
                    acc1[mi][ni] = __builtin_amdgcn_mfma_f32_16x16x32_bf16(ah[mi], bl[ni], acc1[mi][ni], 0, 0, 0);
                    acc1[mi][ni] = __builtin_amdgcn_mfma_f32_16x16x32_bf16(al[mi], bh[ni], acc1[mi][ni], 0, 0, 0);
                }
        }
        __syncthreads();   // previous half's phase-2 readers are done with hidL
        // relu + bias + split -> hidL
#pragma unroll
        for (int ni = 0; ni < 4; ++ni) {
            const int n1 = wn * 64 + ni * 16 + r;
            const float bb = b1[hh * 128 + n1];
#pragma unroll
            for (int mi = 0; mi < 2; ++mi)
#pragma unroll
                for (int reg = 0; reg < 4; ++reg) {
                    const int lrow = wm * 32 + mi * 16 + g * 4 + reg;
                    float v = fmaxf(acc1[mi][ni][reg] + bb, 0.f);
                    unsigned short h = f2bf(v);
                    hidL[0][n1 >> 3][lrow][n1 & 7] = h;
                    hidL[1][n1 >> 3][lrow][n1 & 7] = f2bf(v - bf2f(h));
                }
        }
        __syncthreads();
        // ---------- phase 2: acc2 += hidden_half @ W2[hh*128.., :] ----------
#pragma unroll
        for (int s = 0; s < 4; ++s) {
            bf16x8 a2h[2], a2l[2], b2h[4], b2l[4];
#pragma unroll
            for (int i = 0; i < 2; ++i) {
                const int ar = wm * 32 + i * 16 + r;
                a2h[i] = *(const bf16x8*)&hidL[0][s * 4 + g][ar][0];
                a2l[i] = *(const bf16x8*)&hidL[1][s * 4 + g][ar][0];
            }
#pragma unroll
            for (int i = 0; i < 4; ++i) {
                const int n2 = wn * 64 + i * 16 + r;
                const size_t wo2 = (size_t)n2 * 256 + hh * 128 + s * 32 + g * 8;
                b2h[i] = *(const bf16x8*)(W2hi + wo2);
                b2l[i] = *(const bf16x8*)(W2lo + wo2);
            }
#pragma unroll
            for (int mi = 0; mi < 2; ++mi)
#pragma unroll
                for (int ni = 0; ni < 4; ++ni) {
                    acc2[mi][ni] = __builtin_amdgcn_mfma_f32_16x16x32_bf16(a2h[mi], b2h[ni], acc2[mi][ni], 0, 0, 0);
                    acc2[mi][ni] = __builtin_amdgcn_mfma_f32_16x16x32_bf16(a2h[mi], b2l[ni], acc2[mi][ni], 0, 0, 0);
                    acc2[mi][ni] = __builtin_amdgcn_mfma_f32_16x16x32_bf16(a2l[mi], b2h[ni], acc2[mi][ni], 0, 0, 0);
                }
        }
    }

    // ---------- epilogue: bias, write h2, BN partial sums ----------
    float sl[4] = {0.f, 0.f, 0.f, 0.f}, ql[4] = {0.f, 0.f, 0.f, 0.f};
#pragma unroll
    for (int ni = 0; ni < 4; ++ni) {
        const int n2 = wn * 64 + ni * 16 + r;
        const float bb = b2[n2];
#pragma unroll
        for (int mi = 0; mi < 2; ++mi)
#pragma unroll
            for (int reg = 0; reg < 4; ++reg) {
                const int grow = row0 + wm * 32 + mi * 16 + g * 4 + reg;
                if (grow < M) {
                    float v = acc2[mi][ni][reg] + bb;
                    Of[(size_t)grow * GHC + n2] = v;
                    sl[ni] += v; ql[ni] += v * v;
                }
            }
    }
#pragma unroll
    for (int ni = 0; ni < 4; ++ni) {
        const int n2 = wn * 64 + ni * 16 + r;
        atomicAdd(&sred[n2], sl[ni]);
        atomicAdd(&qred[n2], ql[ni]);
    }
    __syncthreads();
    if (tid < GHC) {
        atomicAdd(&bnsums[tid], sred[tid]);
        atomicAdd(&bnsums[GHC + tid], qred[tid]);
    }
}

// ==================== BN finalize ====================
__global__ void bn_finalize_kernel(const float* __restrict__ sums,
    const float* __restrict__ gamma, const float* __restrict__ beta,
    float* __restrict__ ss) {
    int f = threadIdx.x;
    if (f < GHC) {
        float mu = sums[f] * (1.f / N_NODES);
        float var = sums[GHC + f] * (1.f / N_NODES) - mu * mu;
        float sc = gamma[f] * rsqrtf(var + BN_EPS);
        ss[f] = sc;
        ss[GHC + f] = beta[f] - mu * sc;
    }
}

// ==================== per-graph mean pool with inline BN (batch sorted) ====================
__global__ __launch_bounds__(128)
void pool_kernel(const float* __restrict__ h2, const float* __restrict__ ss,
                 const int* __restrict__ gptr, float* __restrict__ z, int loff) {
    int g = blockIdx.x;
    int f = threadIdx.x;
    float sc = ss[f], sh = ss[GHC + f];
    int s = gptr[g], e = gptr[g + 1];
    float acc = 0.f;
    for (int i = s; i < e; ++i) acc += fmaxf(h2[(size_t)i * GHC + f] * sc + sh, 0.f);
    z[(size_t)g * (N_LAYERS * GHC) + loff + f] = acc / fmaxf((float)(e - s), 1.f);
}

// ==================== fp32 GEMM 64x64 (head, tiny) ====================
template<bool RELU>
__global__ __launch_bounds__(256)
void gemm64_kernel(const float* __restrict__ A, const float* __restrict__ W,
                   const float* __restrict__ bias, float* __restrict__ C,
                   int M, int K, int N) {
    __shared__ float As[16][68];
    __shared__ float Bs[16][64];
    const int tid = threadIdx.x;
    const int row0 = blockIdx.x * 64;
    const int col0 = blockIdx.y * 64;
    const int tx = tid & 15;
    const int ty = tid >> 4;
    const int lm = tid >> 2;
    const int lk = (tid & 3) * 4;
    const int bkr = tid >> 4;
    const int bnc = (tid & 15) * 4;

    float acc[4][4];
#pragma unroll
    for (int i = 0; i < 4; ++i)
#pragma unroll
        for (int j = 0; j < 4; ++j) acc[i][j] = 0.f;

    const int arow = row0 + lm;
    for (int k0 = 0; k0 < K; k0 += 16) {
        if (arow < M) {
            float4 v = *(const float4*)(A + (size_t)arow * K + k0 + lk);
            As[lk + 0][lm] = v.x; As[lk + 1][lm] = v.y;
            As[lk + 2][lm] = v.z; As[lk + 3][lm] = v.w;
        } else {
#pragma unroll
            for (int j = 0; j < 4; ++j) As[lk + j][lm] = 0.f;
        }
        *(float4*)&Bs[bkr][bnc] = *(const float4*)(W + (size_t)(k0 + bkr) * N + col0 + bnc);
        __syncthreads();
#pragma unroll
        for (int kk = 0; kk < 16; ++kk) {
            float a[4], b[4];
            *(float4*)&a[0] = *(const float4*)&As[kk][ty * 4];
            *(float4*)&b[0] = *(const float4*)&Bs[kk][tx * 4];
#pragma unroll
            for (int i = 0; i < 4; ++i)
#pragma unroll
                for (int j = 0; j < 4; ++j)
                    acc[i][j] = fmaf(a[i], b[j], acc[i][j]);
        }
        __syncthreads();
    }
    float4 bv = *(const float4*)(bias + col0 + tx * 4);
    float bb[4] = {bv.x, bv.y, bv.z, bv.w};
#pragma unroll
    for (int i = 0; i < 4; ++i) {
        int row = row0 + ty * 4 + i;
        if (row < M) {
            float o[4];
#pragma unroll
            for (int j = 0; j < 4; ++j) {
                float t = acc[i][j] + bb[j];
                o[j] = RELU ? fmaxf(t, 0.f) : t;
            }
            *(float4*)(C + (size_t)row * N + col0 + tx * 4) = *(float4*)&o[0];
        }
    }
}

extern "C" void kernel_launch(void* const* d_in, const int* in_sizes, int n_in,
                              void* d_out, int out_size, void* d_ws, size_t ws_size,
                              hipStream_t stream)
{
    const float* x = (const float*)d_in[0];
    const int* edge = (const int*)d_in[1];
    const int* batch = (const int*)d_in[2];
    const float* W1_0 = (const float*)d_in[3];
    const float* b1_0 = (const float*)d_in[4];
    const float* W2_0 = (const float*)d_in[5];
    const float* b2_0 = (const float*)d_in[6];
    const float* W1s = (const float*)d_in[7];
    const float* b1s = (const float*)d_in[8];
    const float* W2s = (const float*)d_in[9];
    const float* b2s = (const float*)d_in[10];
    const float* gamma = (const float*)d_in[11];
    const float* beta = (const float*)d_in[12];
    const float* Wm1 = (const float*)d_in[13];
    const float* bm1 = (const float*)d_in[14];
    const float* Wm2 = (const float*)d_in[15];
    const float* bm2 = (const float*)d_in[16];
    const int* srcI = edge;
    const int* dstI = edge + N_EDGES;

    // ---- workspace layout (~115 MB) ----
    unsigned short* agg_hi = (unsigned short*)d_ws;              // N*128 bf16
    unsigned short* agg_lo = agg_hi + (size_t)N_NODES * GHC;     // N*128 bf16
    float* h2 = (float*)(agg_lo + (size_t)N_NODES * GHC);        // N*128 fp32
    float* z = h2 + (size_t)N_NODES * GHC;                       // 1024*640
    float* zh = z + (size_t)N_GRAPHS * N_LAYERS * GHC;           // 1024*512
    float* bnsums = zh + (size_t)N_GRAPHS * NHID;                // 256
    float* bnss = bnsums + 2 * GHC;                              // 256
    unsigned short* w1t_hi = (unsigned short*)(bnss + 2 * GHC);  // 256*128
    unsigned short* w1t_lo = w1t_hi + 256 * GHC;
    unsigned short* w2t_hi = w1t_lo + 256 * GHC;                 // 128*256
    unsigned short* w2t_lo = w2t_hi + 256 * GHC;
    int* ideg = (int*)(w2t_lo + 256 * GHC);                      // N
    int* iptr = ideg + N_NODES;                                  // N+1
    int* iadj = iptr + N_NODES + 1;                              // E
    int* ibtot = iadj + N_EDGES;                                 // 128
    int* igptr = ibtot + 128;                                    // G+1

    // ---- CSR + graph ptr build ----
    hipMemsetAsync(ideg, 0, N_NODES * sizeof(int), stream);
    deg_kernel<<<(N_EDGES + 255) / 256, 256, 0, stream>>>(dstI, ideg);
    scan1_kernel<<<NCHUNKS, SCHUNK, 0, stream>>>(ideg, iptr, ibtot);
    scan2_kernel<<<1, 128, 0, stream>>>(ibtot);
    scan3_kernel<<<(N_NODES + 255) / 256, 256, 0, stream>>>(iptr, ibtot);
    hipMemcpyAsync(ideg, iptr, N_NODES * sizeof(int), hipMemcpyDeviceToDevice, stream);
    fill_kernel<<<(N_EDGES + 255) / 256, 256, 0, stream>>>(srcI, dstI, ideg, iadj);
    gptr_kernel<<<(N_GRAPHS + 1 + 255) / 256, 256, 0, stream>>>(batch, igptr);

    const int MB = (N_NODES + 127) / 128;   // 782
    for (int l = 0; l < N_LAYERS; ++l) {
        const int F = (l == 0) ? F_IN : GHC;
        const float* W1 = (l == 0) ? W1_0 : W1s + (size_t)(l - 1) * GHC * 2 * GHC;
        const float* b1 = (l == 0) ? b1_0 : b1s + (size_t)(l - 1) * 2 * GHC;
        const float* W2 = (l == 0) ? W2_0 : W2s + (size_t)(l - 1) * 2 * GHC * GHC;
        const float* b2 = (l == 0) ? b2_0 : b2s + (size_t)(l - 1) * GHC;

        wconv_kernel<<<(F * 2 * GHC + 255) / 256, 256, 0, stream>>>(W1, w1t_hi, w1t_lo, F, 2 * GHC);
        wconv_kernel<<<(2 * GHC * GHC + 255) / 256, 256, 0, stream>>>(W2, w2t_hi, w2t_lo, 2 * GHC, GHC);

        if (l == 0)
            gather_agg_kernel<F_IN, false><<<(N_NODES + 31) / 32, 256, 0, stream>>>(x, iptr, iadj, nullptr, agg_hi, agg_lo);
        else
            gather_agg_kernel<GHC, true><<<(N_NODES + 7) / 8, 256, 0, stream>>>(h2, iptr, iadj, bnss, agg_hi, agg_lo);

        hipMemsetAsync(bnsums, 0, sizeof(float) * 2 * GHC, stream);
        if (l == 0)
            fused_mlp_kernel<F_IN><<<MB, 512, 0, stream>>>(agg_hi, agg_lo, w1t_hi, w1t_lo, w2t_hi, w2t_lo,
                                                           b1, b2, h2, bnsums, N_NODES);
        else
            fused_mlp_kernel<GHC><<<MB, 512, 0, stream>>>(agg_hi, agg_lo, w1t_hi, w1t_lo, w2t_hi, w2t_lo,
                                                          b1, b2, h2, bnsums, N_NODES);

        bn_finalize_kernel<<<1, GHC, 0, stream>>>(bnsums, gamma + l * GHC, beta + l * GHC, bnss);
        pool_kernel<<<N_GRAPHS, 128, 0, stream>>>(h2, bnss, igptr, z, l * GHC);
    }

    dim3 gh1(N_GRAPHS / 64, NHID / 64);
    gemm64_kernel<true><<<gh1, 256, 0, stream>>>(z, Wm1, bm1, zh, N_GRAPHS, N_LAYERS * GHC, NHID);
    dim3 gh2(N_GRAPHS / 64, NOUT / 64);
    gemm64_kernel<false><<<gh2, 256, 0, stream>>>(zh, Wm2, bm2, (float*)d_out, N_GRAPHS, NHID, NOUT);
}

// Round 11
// 1385.106 us; speedup vs baseline: 1.1205x; 1.1205x over previous
//
#include <hip/hip_runtime.h>

#define N_NODES 100000
#define N_EDGES 600000
#define N_GRAPHS 1024
#define F_IN 32
#define GHC 128
#define NHID 512
#define NOUT 256
#define N_LAYERS 5
#define BN_EPS 1e-5f

typedef __attribute__((ext_vector_type(4))) float f32x4;
typedef __attribute__((ext_vector_type(8))) short bf16x8;

__device__ __forceinline__ unsigned short f2bf(float f) {
    unsigned int u = __float_as_uint(f);
    u = u + 0x7fffu + ((u >> 16) & 1u);
    return (unsigned short)(u >> 16);
}
__device__ __forceinline__ float bf2f(unsigned short h) {
    return __uint_as_float(((unsigned int)h) << 16);
}

// ==================== CSR build ====================
__global__ void deg_kernel(const int* __restrict__ dst, int* __restrict__ deg) {
    int e = blockIdx.x * blockDim.x + threadIdx.x;
    if (e < N_EDGES) atomicAdd(&deg[dst[e]], 1);
}

#define SCHUNK 1024
#define NCHUNKS ((N_NODES + SCHUNK - 1) / SCHUNK)   // 98

__global__ __launch_bounds__(1024)
void scan1_kernel(const int* __restrict__ deg, int* __restrict__ ptr, int* __restrict__ btot) {
    __shared__ int buf[SCHUNK];
    int t = threadIdx.x;
    int i = blockIdx.x * SCHUNK + t;
    int v = (i < N_NODES) ? deg[i] : 0;
    buf[t] = v;
    __syncthreads();
    for (int off = 1; off < SCHUNK; off <<= 1) {
        int u = (t >= off) ? buf[t - off] : 0;
        __syncthreads();
        buf[t] += u;
        __syncthreads();
    }
    if (i < N_NODES) ptr[i + 1] = buf[t];
    if (t == SCHUNK - 1) btot[blockIdx.x] = buf[t];
}

__global__ __launch_bounds__(128)
void scan2_kernel(int* __restrict__ btot) {
    __shared__ int buf[128];
    int t = threadIdx.x;
    int v = (t < NCHUNKS) ? btot[t] : 0;
    buf[t] = v;
    __syncthreads();
    for (int off = 1; off < 128; off <<= 1) {
        int u = (t >= off) ? buf[t - off] : 0;
        __syncthreads();
        buf[t] += u;
        __syncthreads();
    }
    if (t < NCHUNKS) btot[t] = buf[t] - v;
}

__global__ void scan3_kernel(int* __restrict__ ptr, const int* __restrict__ btot) {
    int i = blockIdx.x * blockDim.x + threadIdx.x;
    if (i < N_NODES) ptr[i + 1] += btot[i >> 10];
    if (i == 0) ptr[0] = 0;
}

__global__ void fill_kernel(const int* __restrict__ src, const int* __restrict__ dst,
                            int* __restrict__ cur, int* __restrict__ adj) {
    int e = blockIdx.x * blockDim.x + threadIdx.x;
    if (e >= N_EDGES) return;
    int p = atomicAdd(&cur[dst[e]], 1);
    adj[p] = src[e];
}

__global__ void gptr_kernel(const int* __restrict__ batch, int* __restrict__ gptr) {
    int g = blockIdx.x * blockDim.x + threadIdx.x;
    if (g > N_GRAPHS) return;
    int lo = 0, hi = N_NODES;
    while (lo < hi) { int mid = (lo + hi) >> 1; if (batch[mid] < g) lo = mid + 1; else hi = mid; }
    gptr[g] = lo;
}

// ==================== weight transpose + bf16 split: W[K][N] -> Wt_hi/lo [N][K] ====================
__global__ void wconv_kernel(const float* __restrict__ W, unsigned short* __restrict__ thi,
                             unsigned short* __restrict__ tlo, int K, int N) {
    int i = blockIdx.x * blockDim.x + threadIdx.x;
    if (i >= K * N) return;
    int k = i / N, n = i - k * N;
    float v = W[i];
    unsigned short h = f2bf(v);
    thi[(size_t)n * K + k] = h;
    tlo[(size_t)n * K + k] = f2bf(v - bf2f(h));
}

// ==================== gather aggregation (+ inline BN of previous layer) -> bf16 planes ====================
template<int F, bool BN>
__global__ __launch_bounds__(256)
void gather_agg_kernel(const float* __restrict__ x, const int* __restrict__ ptr,
                       const int* __restrict__ adj, const float* __restrict__ ss,
                       unsigned short* __restrict__ ahi, unsigned short* __restrict__ alo) {
    constexpr int F4 = F / 4;
    constexpr int NPB = 256 / F4;
    int f4 = threadIdx.x % F4;
    int n = blockIdx.x * NPB + threadIdx.x / F4;
    if (n >= N_NODES) return;
    const int fo = f4 * 4;
    float4 sc, sh;
    if (BN) { sc = *(const float4*)(ss + fo); sh = *(const float4*)(ss + GHC + fo); }
    float4 acc = *(const float4*)(x + (size_t)n * F + fo);
    if (BN) {
        acc.x = fmaxf(acc.x * sc.x + sh.x, 0.f); acc.y = fmaxf(acc.y * sc.y + sh.y, 0.f);
        acc.z = fmaxf(acc.z * sc.z + sh.z, 0.f); acc.w = fmaxf(acc.w * sc.w + sh.w, 0.f);
    }
    int p1 = ptr[n + 1];
    for (int p = ptr[n]; p < p1; ++p) {
        int s = adj[p];
        float4 v = *(const float4*)(x + (size_t)s * F + fo);
        if (BN) {
            v.x = fmaxf(v.x * sc.x + sh.x, 0.f); v.y = fmaxf(v.y * sc.y + sh.y, 0.f);
            v.z = fmaxf(v.z * sc.z + sh.z, 0.f); v.w = fmaxf(v.w * sc.w + sh.w, 0.f);
        }
        acc.x += v.x; acc.y += v.y; acc.z += v.z; acc.w += v.w;
    }
    ushort4 h4, l4;
    h4.x = f2bf(acc.x); l4.x = f2bf(acc.x - bf2f(h4.x));
    h4.y = f2bf(acc.y); l4.y = f2bf(acc.y - bf2f(h4.y));
    h4.z = f2bf(acc.z); l4.z = f2bf(acc.z - bf2f(h4.z));
    h4.w = f2bf(acc.w); l4.w = f2bf(acc.w - bf2f(h4.w));
    *(ushort4*)(ahi + (size_t)n * F + fo) = h4;
    *(ushort4*)(alo + (size_t)n * F + fo) = l4;
}

// ==================== fused MLP v4: h2 = (relu(A@W1+b1))@W2 + b2, + BN stats ====================
// Back to the proven v2 shape: 256 threads = 4 waves (2x2 of 64x64), two 128-col hidden
// halves in 64 KB LDS, acc2 persists in registers. NEW vs v2:
//  (a) K is a template param and the phase-1 K-loop is fully unrolled -> compiler can
//      software-pipeline the 16 scattered global fragment loads under the 48 MFMAs.
//  (b) hidL is kg-XOR swizzled (idx ^= (kg&7)<<3 halfwords) to break the ~8-way bank
//      conflict of the transposed ds_write_b16 epilogue; reads stay 16B-contiguous.
// __launch_bounds__(256,2) keeps a 256-reg budget: NO spills (round-10 lesson).
// 3-term split: X*Y ~= Xh*Yh + Xh*Yl + Xl*Yh (fp32-level accuracy).
template<int K>
__global__ __launch_bounds__(256, 2)
void fused_mlp_kernel(const unsigned short* __restrict__ Ahi, const unsigned short* __restrict__ Alo,
                      const unsigned short* __restrict__ W1hi, const unsigned short* __restrict__ W1lo,
                      const unsigned short* __restrict__ W2hi, const unsigned short* __restrict__ W2lo,
                      const float* __restrict__ b1, const float* __restrict__ b2,
                      float* __restrict__ Of, float* __restrict__ bnsums,
                      int M)
{
    __shared__ __align__(16) unsigned short hidS[2][16384];   // 64 KB: [plane][kg*1024+row*8+w] swizzled
    __shared__ float sred[GHC], qred[GHC];

    const int tid = threadIdx.x;
    const int wv = tid >> 6, lane = tid & 63;
    const int r = lane & 15, g = lane >> 4;
    const int wm = wv >> 1, wn = wv & 1;
    const int row0 = blockIdx.x * 128;

    if (tid < GHC) { sred[tid] = 0.f; qred[tid] = 0.f; }

    int arows[4];
#pragma unroll
    for (int i = 0; i < 4; ++i) {
        int rr = row0 + wm * 64 + i * 16 + r;
        arows[i] = rr < M ? rr : M - 1;
    }

    f32x4 acc2[4][4];
#pragma unroll
    for (int mi = 0; mi < 4; ++mi)
#pragma unroll
        for (int ni = 0; ni < 4; ++ni) acc2[mi][ni] = 0.f;

#pragma unroll
    for (int hh = 0; hh < 2; ++hh) {
        // ---------- phase 1: hidden half = A @ W1[:, hh*128 + 0..127] ----------
        f32x4 acc1[4][4];
#pragma unroll
        for (int mi = 0; mi < 4; ++mi)
#pragma unroll
            for (int ni = 0; ni < 4; ++ni) acc1[mi][ni] = 0.f;

#pragma unroll
        for (int k0 = 0; k0 < K; k0 += 32) {
            bf16x8 ah[4], al[4], bh[4], bl[4];
#pragma unroll
            for (int i = 0; i < 4; ++i) {
                const size_t ao = (size_t)arows[i] * K + k0 + g * 8;
                ah[i] = *(const bf16x8*)(Ahi + ao);
                al[i] = *(const bf16x8*)(Alo + ao);
            }
#pragma unroll
            for (int i = 0; i < 4; ++i) {
                const int n1g = hh * 128 + wn * 64 + i * 16 + r;
                const size_t wo = (size_t)n1g * K + k0 + g * 8;
                bh[i] = *(const bf16x8*)(W1hi + wo);
                bl[i] = *(const bf16x8*)(W1lo + wo);
            }
#pragma unroll
            for (int mi = 0; mi < 4; ++mi)
#pragma unroll
                for (int ni = 0; ni < 4; ++ni) {
                    acc1[mi][ni] = __builtin_amdgcn_mfma_f32_16x16x32_bf16(ah[mi], bh[ni], acc1[mi][ni], 0, 0, 0);
                    acc1[mi][ni] = __builtin_amdgcn_mfma_f32_16x16x32_bf16(ah[mi], bl[ni], acc1[mi][ni], 0, 0, 0);
                    acc1[mi][ni] = __builtin_amdgcn_mfma_f32_16x16x32_bf16(al[mi], bh[ni], acc1[mi][ni], 0, 0, 0);
                }
        }
        __syncthreads();   // previous half's phase-2 readers are done with hidS
        // relu + bias + split -> hidS (swizzled)
#pragma unroll
        for (int ni = 0; ni < 4; ++ni) {
            const int n1 = wn * 64 + ni * 16 + r;
            const int kg = n1 >> 3, w = n1 & 7;
            const float bb = b1[hh * 128 + n1];
#pragma unroll
            for (int mi = 0; mi < 4; ++mi)
#pragma unroll
                for (int reg = 0; reg < 4; ++reg) {
                    const int lrow = wm * 64 + mi * 16 + g * 4 + reg;
                    const int base = (kg * 1024 + lrow * 8) ^ ((kg & 7) << 3);
                    float v = fmaxf(acc1[mi][ni][reg] + bb, 0.f);
                    unsigned short h = f2bf(v);
                    hidS[0][base + w] = h;
                    hidS[1][base + w] = f2bf(v - bf2f(h));
                }
        }
        __syncthreads();
        // ---------- phase 2: acc2 += hidden_half @ W2[hh*128.., :] ----------
#pragma unroll
        for (int s = 0; s < 4; ++s) {
            const int kg = s * 4 + g;
            bf16x8 a2h[4], a2l[4], b2h[4], b2l[4];
#pragma unroll
            for (int i = 0; i < 4; ++i) {
                const int ar = wm * 64 + i * 16 + r;
                const int rbase = (kg * 1024 + ar * 8) ^ ((kg & 7) << 3);
                a2h[i] = *(const bf16x8*)&hidS[0][rbase];
                a2l[i] = *(const bf16x8*)&hidS[1][rbase];
            }
#pragma unroll
            for (int i = 0; i < 4; ++i) {
                const int n2 = wn * 64 + i * 16 + r;
                const size_t wo2 = (size_t)n2 * 256 + hh * 128 + s * 32 + g * 8;
                b2h[i] = *(const bf16x8*)(W2hi + wo2);
                b2l[i] = *(const bf16x8*)(W2lo + wo2);
            }
#pragma unroll
            for (int mi = 0; mi < 4; ++mi)
#pragma unroll
                for (int ni = 0; ni < 4; ++ni) {
                    acc2[mi][ni] = __builtin_amdgcn_mfma_f32_16x16x32_bf16(a2h[mi], b2h[ni], acc2[mi][ni], 0, 0, 0);
                    acc2[mi][ni] = __builtin_amdgcn_mfma_f32_16x16x32_bf16(a2h[mi], b2l[ni], acc2[mi][ni], 0, 0, 0);
                    acc2[mi][ni] = __builtin_amdgcn_mfma_f32_16x16x32_bf16(a2l[mi], b2h[ni], acc2[mi][ni], 0, 0, 0);
                }
        }
    }

    // ---------- epilogue: bias, write h2, BN partial sums ----------
    float sl[4] = {0.f, 0.f, 0.f, 0.f}, ql[4] = {0.f, 0.f, 0.f, 0.f};
#pragma unroll
    for (int ni = 0; ni < 4; ++ni) {
        const int n2 = wn * 64 + ni * 16 + r;
        const float bb = b2[n2];
#pragma unroll
        for (int mi = 0; mi < 4; ++mi)
#pragma unroll
            for (int reg = 0; reg < 4; ++reg) {
                const int grow = row0 + wm * 64 + mi * 16 + g * 4 + reg;
                if (grow < M) {
                    float v = acc2[mi][ni][reg] + bb;
                    Of[(size_t)grow * GHC + n2] = v;
                    sl[ni] += v; ql[ni] += v * v;
                }
            }
    }
#pragma unroll
    for (int ni = 0; ni < 4; ++ni) {
        const int n2 = wn * 64 + ni * 16 + r;
        atomicAdd(&sred[n2], sl[ni]);
        atomicAdd(&qred[n2], ql[ni]);
    }
    __syncthreads();
    if (tid < GHC) {
        atomicAdd(&bnsums[tid], sred[tid]);
        atomicAdd(&bnsums[GHC + tid], qred[tid]);
    }
}

// ==================== BN finalize ====================
__global__ void bn_finalize_kernel(const float* __restrict__ sums,
    const float* __restrict__ gamma, const float* __restrict__ beta,
    float* __restrict__ ss) {
    int f = threadIdx.x;
    if (f < GHC) {
        float mu = sums[f] * (1.f / N_NODES);
        float var = sums[GHC + f] * (1.f / N_NODES) - mu * mu;
        float sc = gamma[f] * rsqrtf(var + BN_EPS);
        ss[f] = sc;
        ss[GHC + f] = beta[f] - mu * sc;
    }
}

// ==================== per-graph mean pool with inline BN (batch sorted) ====================
__global__ __launch_bounds__(128)
void pool_kernel(const float* __restrict__ h2, const float* __restrict__ ss,
                 const int* __restrict__ gptr, float* __restrict__ z, int loff) {
    int g = blockIdx.x;
    int f = threadIdx.x;
    float sc = ss[f], sh = ss[GHC + f];
    int s = gptr[g], e = gptr[g + 1];
    float acc = 0.f;
    for (int i = s; i < e; ++i) acc += fmaxf(h2[(size_t)i * GHC + f] * sc + sh, 0.f);
    z[(size_t)g * (N_LAYERS * GHC) + loff + f] = acc / fmaxf((float)(e - s), 1.f);
}

// ==================== fp32 GEMM 64x64 (head, tiny) ====================
template<bool RELU>
__global__ __launch_bounds__(256)
void gemm64_kernel(const float* __restrict__ A, const float* __restrict__ W,
                   const float* __restrict__ bias, float* __restrict__ C,
                   int M, int K, int N) {
    __shared__ float As[16][68];
    __shared__ float Bs[16][64];
    const int tid = threadIdx.x;
    const int row0 = blockIdx.x * 64;
    const int col0 = blockIdx.y * 64;
    const int tx = tid & 15;
    const int ty = tid >> 4;
    const int lm = tid >> 2;
    const int lk = (tid & 3) * 4;
    const int bkr = tid >> 4;
    const int bnc = (tid & 15) * 4;

    float acc[4][4];
#pragma unroll
    for (int i = 0; i < 4; ++i)
#pragma unroll
        for (int j = 0; j < 4; ++j) acc[i][j] = 0.f;

    const int arow = row0 + lm;
    for (int k0 = 0; k0 < K; k0 += 16) {
        if (arow < M) {
            float4 v = *(const float4*)(A + (size_t)arow * K + k0 + lk);
            As[lk + 0][lm] = v.x; As[lk + 1][lm] = v.y;
            As[lk + 2][lm] = v.z; As[lk + 3][lm] = v.w;
        } else {
#pragma unroll
            for (int j = 0; j < 4; ++j) As[lk + j][lm] = 0.f;
        }
        *(float4*)&Bs[bkr][bnc] = *(const float4*)(W + (size_t)(k0 + bkr) * N + col0 + bnc);
        __syncthreads();
#pragma unroll
        for (int kk = 0; kk < 16; ++kk) {
            float a[4], b[4];
            *(float4*)&a[0] = *(const float4*)&As[kk][ty * 4];
            *(float4*)&b[0] = *(const float4*)&Bs[kk][tx * 4];
#pragma unroll
            for (int i = 0; i < 4; ++i)
#pragma unroll
                for (int j = 0; j < 4; ++j)
                    acc[i][j] = fmaf(a[i], b[j], acc[i][j]);
        }
        __syncthreads();
    }
    float4 bv = *(const float4*)(bias + col0 + tx * 4);
    float bb[4] = {bv.x, bv.y, bv.z, bv.w};
#pragma unroll
    for (int i = 0; i < 4; ++i) {
        int row = row0 + ty * 4 + i;
        if (row < M) {
            float o[4];
#pragma unroll
            for (int j = 0; j < 4; ++j) {
                float t = acc[i][j] + bb[j];
                o[j] = RELU ? fmaxf(t, 0.f) : t;
            }
            *(float4*)(C + (size_t)row * N + col0 + tx * 4) = *(float4*)&o[0];
        }
    }
}

extern "C" void kernel_launch(void* const* d_in, const int* in_sizes, int n_in,
                              void* d_out, int out_size, void* d_ws, size_t ws_size,
                              hipStream_t stream)
{
    const float* x = (const float*)d_in[0];
    const int* edge = (const int*)d_in[1];
    const int* batch = (const int*)d_in[2];
    const float* W1_0 = (const float*)d_in[3];
    const float* b1_0 = (const float*)d_in[4];
    const float* W2_0 = (const float*)d_in[5];
    const float* b2_0 = (const float*)d_in[6];
    const float* W1s = (const float*)d_in[7];
    const float* b1s = (const float*)d_in[8];
    const float* W2s = (const float*)d_in[9];
    const float* b2s = (const float*)d_in[10];
    const float* gamma = (const float*)d_in[11];
    const float* beta = (const float*)d_in[12];
    const float* Wm1 = (const float*)d_in[13];
    const float* bm1 = (const float*)d_in[14];
    const float* Wm2 = (const float*)d_in[15];
    const float* bm2 = (const float*)d_in[16];
    const int* srcI = edge;
    const int* dstI = edge + N_EDGES;

    // ---- workspace layout (~115 MB) ----
    unsigned short* agg_hi = (unsigned short*)d_ws;              // N*128 bf16
    unsigned short* agg_lo = agg_hi + (size_t)N_NODES * GHC;     // N*128 bf16
    float* h2 = (float*)(agg_lo + (size_t)N_NODES * GHC);        // N*128 fp32
    float* z = h2 + (size_t)N_NODES * GHC;                       // 1024*640
    float* zh = z + (size_t)N_GRAPHS * N_LAYERS * GHC;           // 1024*512
    float* bnsums = zh + (size_t)N_GRAPHS * NHID;                // 256
    float* bnss = bnsums + 2 * GHC;                              // 256
    unsigned short* w1t_hi = (unsigned short*)(bnss + 2 * GHC);  // 256*128
    unsigned short* w1t_lo = w1t_hi + 256 * GHC;
    unsigned short* w2t_hi = w1t_lo + 256 * GHC;                 // 128*256
    unsigned short* w2t_lo = w2t_hi + 256 * GHC;
    int* ideg = (int*)(w2t_lo + 256 * GHC);                      // N
    int* iptr = ideg + N_NODES;                                  // N+1
    int* iadj = iptr + N_NODES + 1;                              // E
    int* ibtot = iadj + N_EDGES;                                 // 128
    int* igptr = ibtot + 128;                                    // G+1

    // ---- CSR + graph ptr build ----
    hipMemsetAsync(ideg, 0, N_NODES * sizeof(int), stream);
    deg_kernel<<<(N_EDGES + 255) / 256, 256, 0, stream>>>(dstI, ideg);
    scan1_kernel<<<NCHUNKS, SCHUNK, 0, stream>>>(ideg, iptr, ibtot);
    scan2_kernel<<<1, 128, 0, stream>>>(ibtot);
    scan3_kernel<<<(N_NODES + 255) / 256, 256, 0, stream>>>(iptr, ibtot);
    hipMemcpyAsync(ideg, iptr, N_NODES * sizeof(int), hipMemcpyDeviceToDevice, stream);
    fill_kernel<<<(N_EDGES + 255) / 256, 256, 0, stream>>>(srcI, dstI, ideg, iadj);
    gptr_kernel<<<(N_GRAPHS + 1 + 255) / 256, 256, 0, stream>>>(batch, igptr);

    const int MB = (N_NODES + 127) / 128;   // 782
    for (int l = 0; l < N_LAYERS; ++l) {
        const int F = (l == 0) ? F_IN : GHC;
        const float* W1 = (l == 0) ? W1_0 : W1s + (size_t)(l - 1) * GHC * 2 * GHC;
        const float* b1 = (l == 0) ? b1_0 : b1s + (size_t)(l - 1) * 2 * GHC;
        const float* W2 = (l == 0) ? W2_0 : W2s + (size_t)(l - 1) * 2 * GHC * GHC;
        const float* b2 = (l == 0) ? b2_0 : b2s + (size_t)(l - 1) * GHC;

        wconv_kernel<<<(F * 2 * GHC + 255) / 256, 256, 0, stream>>>(W1, w1t_hi, w1t_lo, F, 2 * GHC);
        wconv_kernel<<<(2 * GHC * GHC + 255) / 256, 256, 0, stream>>>(W2, w2t_hi, w2t_lo, 2 * GHC, GHC);

        if (l == 0)
            gather_agg_kernel<F_IN, false><<<(N_NODES + 31) / 32, 256, 0, stream>>>(x, iptr, iadj, nullptr, agg_hi, agg_lo);
        else
            gather_agg_kernel<GHC, true><<<(N_NODES + 7) / 8, 256, 0, stream>>>(h2, iptr, iadj, bnss, agg_hi, agg_lo);

        hipMemsetAsync(bnsums, 0, sizeof(float) * 2 * GHC, stream);
        if (l == 0)
            fused_mlp_kernel<F_IN><<<MB, 256, 0, stream>>>(agg_hi, agg_lo, w1t_hi, w1t_lo, w2t_hi, w2t_lo,
                                                           b1, b2, h2, bnsums, N_NODES);
        else
            fused_mlp_kernel<GHC><<<MB, 256, 0, stream>>>(agg_hi, agg_lo, w1t_hi, w1t_lo, w2t_hi, w2t_lo,
                                                          b1, b2, h2, bnsums, N_NODES);

        bn_finalize_kernel<<<1, GHC, 0, stream>>>(bnsums, gamma + l * GHC, beta + l * GHC, bnss);
        pool_kernel<<<N_GRAPHS, 128, 0, stream>>>(h2, bnss, igptr, z, l * GHC);
    }

    dim3 gh1(N_GRAPHS / 64, NHID / 64);
    gemm64_kernel<true><<<gh1, 256, 0, stream>>>(z, Wm1, bm1, zh, N_GRAPHS, N_LAYERS * GHC, NHID);
    dim3 gh2(N_GRAPHS / 64, NOUT / 64);
    gemm64_kernel<false><<<gh2, 256, 0, stream>>>(zh, Wm2, bm2, (float*)d_out, N_GRAPHS, NHID, NOUT);
}